// Round 2
// baseline (448.072 us; speedup 1.0000x reference)
//
#include <hip/hip_runtime.h>
#include <hip/hip_bf16.h>
#include <math.h>

#define DF 128
#define NC 40
#define PC 20            // classes per plane (2 planes: 40 B rows -> 4 MB/plane, fits one XCD L2)
#define RB 8             // bucket = node >> 8 (256 nodes/bucket)
#define RSZ 256
#define CHUNK 4096       // edges per binning block
#define CAP 12288        // slab capacity per bucket

typedef float f32x4 __attribute__((ext_vector_type(4)));

__device__ __forceinline__ float bf2f(unsigned short h) {
  unsigned int u = ((unsigned int)h) << 16;
  union { unsigned int u; float f; } c; c.u = u; return c.f;
}
__device__ __forceinline__ unsigned short f2bf(float x) {  // round-to-nearest-even
  union { float f; unsigned int u; } c; c.f = x;
  unsigned int u = c.u;
  return (unsigned short)((u + 0x7fffu + ((u >> 16) & 1u)) >> 16);
}
// unpack a dword holding two packed bf16 (lo = bits 0-15, hi = bits 16-31)
__device__ __forceinline__ float blo(unsigned int u) {
  union { unsigned int u; float f; } c; c.u = u << 16; return c.f;
}
__device__ __forceinline__ float bhi(unsigned int u) {
  union { unsigned int u; float f; } c; c.u = u & 0xffff0000u; return c.f;
}

// ---------- pass B: bin edges into per-bucket slab, count totals ----------
__global__ __launch_bounds__(512) void k_binB(
    const int* __restrict__ row, const int* __restrict__ col,
    int* __restrict__ cnt, unsigned int* __restrict__ slab, int E, int NB) {
  __shared__ int colS[CHUNK];   // 16 KB
  __shared__ int hist[512];
  __shared__ int cursor[512];
  int t = threadIdx.x;
  if (t < NB) hist[t] = 0;
  int s = blockIdx.x * CHUNK, e = min(E, s + CHUNK), n = e - s;
  for (int i = t; i < n; i += 512) colS[i] = col[s + i];
  __syncthreads();
  for (int i = t; i < n; i += 512) atomicAdd(&hist[colS[i] >> RB], 1);
  __syncthreads();
  if (t < NB) cursor[t] = hist[t] ? atomicAdd(&cnt[t], hist[t]) : 0;
  __syncthreads();
  for (int i = t; i < n; i += 512) {
    int c = colS[i];
    int b = c >> RB;
    int p = atomicAdd(&cursor[b], 1);
    slab[(size_t)b * CAP + p] = ((unsigned int)row[s + i] << RB) | (unsigned int)(c & (RSZ - 1));
  }
}

// ---------- bucket base scan (single block; NB <= 512) ----------
__global__ __launch_bounds__(512) void k_bucket_scan(
    const int* __restrict__ cnt, int* __restrict__ base,
    int* __restrict__ off, int NB, int N, int E) {
  __shared__ int s[512];
  int t = threadIdx.x;
  int v = (t < NB) ? cnt[t] : 0;
  s[t] = v;
  __syncthreads();
  for (int o = 1; o < 512; o <<= 1) {
    int u = (t >= o) ? s[t - o] : 0;
    __syncthreads();
    s[t] += u;
    __syncthreads();
  }
  if (t < NB) base[t] = s[t] - v;  // exclusive
  if (t == 0) { base[NB] = E; off[N] = E; }
}

// ---------- pass C: per-bucket CSR finalize + dinv ----------
__global__ __launch_bounds__(512) void k_binC(
    const unsigned int* __restrict__ slab, const int* __restrict__ base,
    int* __restrict__ off, int* __restrict__ eidx, float* __restrict__ dinv, int N) {
  __shared__ int hist[RSZ];
  __shared__ int sc[RSZ];
  __shared__ int cur[RSZ];
  int b = blockIdx.x;
  int t = threadIdx.x;
  if (t < RSZ) hist[t] = 0;
  __syncthreads();
  int cb = base[b], ce = base[b + 1];
  int cnt_b = ce - cb;
  const unsigned int* src = slab + (size_t)b * CAP;
  for (int i = t; i < cnt_b; i += 512) atomicAdd(&hist[src[i] & (RSZ - 1)], 1);
  __syncthreads();
  int v = (t < RSZ) ? hist[t] : 0;
  if (t < RSZ) sc[t] = v;
  __syncthreads();
  for (int o = 1; o < RSZ; o <<= 1) {
    int u = (t < RSZ && t >= o) ? sc[t - o] : 0;
    __syncthreads();
    if (t < RSZ) sc[t] += u;
    __syncthreads();
  }
  if (t < RSZ) {
    int pos = cb + sc[t] - v;
    int node = (b << RB) + t;
    if (node < N) {
      off[node] = pos;
      dinv[node] = rsqrtf((float)v + 2.0f);  // degree + 2 self-loops
    }
    cur[t] = pos;
  }
  __syncthreads();
  for (int i = t; i < cnt_b; i += 512) {
    unsigned int en = src[i];
    int p = atomicAdd(&cur[en & (RSZ - 1)], 1);
    eidx[p] = (int)(en >> RB);
  }
}

// ---------- projection first: g0 planes = bf16( dinv[n] * (x[n] @ W^T) ) ----------
// plane p (p=0,1) holds classes [p*20, p*20+20) as 40 B rows: base = g0 + p*N*PC ushorts
__global__ __launch_bounds__(128) void k_xw_scale(
    const float* __restrict__ x, const float* __restrict__ W,
    const float* __restrict__ dinv, unsigned short* __restrict__ g0, int N) {
  __shared__ float4 Ws[NC * (DF / 4)];  // 20 KB
  for (int i = threadIdx.x; i < NC * (DF / 4); i += blockDim.x)
    Ws[i] = ((const float4*)W)[i];
  __syncthreads();
  int node = blockIdx.x * blockDim.x + threadIdx.x;
  if (node >= N) return;
  float acc[NC];
#pragma unroll
  for (int c = 0; c < NC; ++c) acc[c] = 0.f;
  const float4* xr = (const float4*)(x + (size_t)node * DF);
#pragma unroll 1
  for (int ch = 0; ch < 8; ++ch) {
    float4 v0 = xr[ch * 4 + 0];
    float4 v1 = xr[ch * 4 + 1];
    float4 v2 = xr[ch * 4 + 2];
    float4 v3 = xr[ch * 4 + 3];
#pragma unroll
    for (int c = 0; c < NC; ++c) {
      float4 w0 = Ws[c * (DF / 4) + ch * 4 + 0];
      float4 w1 = Ws[c * (DF / 4) + ch * 4 + 1];
      float4 w2 = Ws[c * (DF / 4) + ch * 4 + 2];
      float4 w3 = Ws[c * (DF / 4) + ch * 4 + 3];
      acc[c] += (v0.x * w0.x + v0.y * w0.y + v0.z * w0.z + v0.w * w0.w) +
                (v1.x * w1.x + v1.y * w1.y + v1.z * w1.z + v1.w * w1.w) +
                (v2.x * w2.x + v2.y * w2.y + v2.z * w2.z + v2.w * w2.w) +
                (v3.x * w3.x + v3.y * w3.y + v3.z * w3.z + v3.w * w3.w);
    }
  }
  float di = dinv[node];
  unsigned int pk[NC / 2];
#pragma unroll
  for (int c2 = 0; c2 < NC / 2; ++c2) {
    unsigned int lo = f2bf(di * acc[c2 * 2 + 0]);
    unsigned int hi = f2bf(di * acc[c2 * 2 + 1]);
    pk[c2] = lo | (hi << 16);
  }
  uint2* p0 = (uint2*)g0 + (size_t)node * 5;
  uint2* p1 = (uint2*)g0 + (size_t)N * 5 + (size_t)node * 5;
#pragma unroll
  for (int q = 0; q < 5; ++q) {
    p0[q] = make_uint2(pk[2 * q], pk[2 * q + 1]);
    p1[q] = make_uint2(pk[10 + 2 * q], pk[10 + 2 * q + 1]);
  }
}

// ---------- hop kernel: one wave = one node x one class-plane (20 classes) ----------
// 12 edges x 5 lanes per iteration; each lane loads a uint2 (4 classes, 8 B).
// Block->plane assignment rides blockIdx%8 so XCDs 0-3 only touch plane 0,
// XCDs 4-7 only plane 1 (round-robin dispatch heuristic; correctness-safe).
template<int FINAL>
__global__ __launch_bounds__(256) void k_hop(
    const int* __restrict__ off, const int* __restrict__ eidx,
    const float* __restrict__ dinv, const unsigned short* __restrict__ gin,
    unsigned short* __restrict__ gout, float* __restrict__ logits,
    const float* __restrict__ bias, int N, int NBH) {
  int bid = blockIdx.x;
  int slot8 = bid & 7;
  int half = slot8 >> 2;                       // plane id 0/1
  int nbi = ((bid >> 3) << 2) + (slot8 & 3);   // node-block index within plane
  if (nbi >= NBH) return;
  int lane = threadIdx.x & 63;
  int node = (nbi << 2) + (threadIdx.x >> 6);
  if (node >= N) return;
  int slot = lane / 5;                         // edge slot 0..11 (12), lanes 60-63 idle
  unsigned j = (unsigned)(lane - slot * 5);    // uint2 index within 40 B row
  const uint2* plane = (const uint2*)gin + (size_t)half * ((size_t)N * 5);
  int s = __builtin_amdgcn_readfirstlane(off[node]);
  int e = __builtin_amdgcn_readfirstlane(off[node + 1]);
  float a0 = 0.f, a1 = 0.f, a2 = 0.f, a3 = 0.f;
  unsigned selfoff = (unsigned)node * 5u + j;
  if (slot == 0) {                             // double self-loop term
    uint2 v = plane[selfoff];
    a0 = 2.f * blo(v.x); a1 = 2.f * bhi(v.x);
    a2 = 2.f * blo(v.y); a3 = 2.f * bhi(v.y);
  }
  int i = s;
  if (slot < 12) {
    for (; i + 12 <= e; i += 12) {
      int r = __builtin_nontemporal_load(eidx + i + slot);
      uint2 v = plane[(unsigned)r * 5u + j];
      a0 += blo(v.x); a1 += bhi(v.x); a2 += blo(v.y); a3 += bhi(v.y);
    }
    if (slot < e - i) {
      int r = __builtin_nontemporal_load(eidx + i + slot);
      uint2 v = plane[(unsigned)r * 5u + j];
      a0 += blo(v.x); a1 += bhi(v.x); a2 += blo(v.y); a3 += bhi(v.y);
    }
  }
  // reduce the 12 edge slots (lane stride 5) down to lanes 0..4
  int l30 = (lane + 30) & 63, l15 = (lane + 15) & 63;
  a0 += __shfl(a0, l30, 64); a1 += __shfl(a1, l30, 64);
  a2 += __shfl(a2, l30, 64); a3 += __shfl(a3, l30, 64);
  a0 += __shfl(a0, l15, 64); a1 += __shfl(a1, l15, 64);
  a2 += __shfl(a2, l15, 64); a3 += __shfl(a3, l15, 64);
  int l5 = (lane + 5) & 63, l10 = (lane + 10) & 63;
  a0 = a0 + __shfl(a0, l5, 64) + __shfl(a0, l10, 64);
  a1 = a1 + __shfl(a1, l5, 64) + __shfl(a1, l10, 64);
  a2 = a2 + __shfl(a2, l5, 64) + __shfl(a2, l10, 64);
  a3 = a3 + __shfl(a3, l5, 64) + __shfl(a3, l10, 64);
  if (slot == 0) {                             // lanes 0..4 hold classes 4j..4j+3 of this plane
    float di = dinv[node];
    if (FINAL) {
      float4 bb = ((const float4*)bias)[half * 5 + (int)j];
      f32x4 lg = { di * a0 + bb.x, di * a1 + bb.y,
                   di * a2 + bb.z, di * a3 + bb.w };
      f32x4* dst = (f32x4*)(logits + (size_t)node * NC + half * PC + 4u * j);
      __builtin_nontemporal_store(lg, dst);    // streamed; don't evict the plane
    } else {
      float sc = di * di;
      unsigned lo = (unsigned)f2bf(sc * a0) | ((unsigned)f2bf(sc * a1) << 16);
      unsigned hi = (unsigned)f2bf(sc * a2) | ((unsigned)f2bf(sc * a3) << 16);
      unsigned long long pk = (unsigned long long)lo | ((unsigned long long)hi << 32);
      unsigned long long* dst =
          (unsigned long long*)((uint2*)gout + (size_t)half * ((size_t)N * 5) + selfoff);
      __builtin_nontemporal_store(pk, dst);
    }
  }
}

// ---------- epilogue: log_softmax over f32 logits ----------
__global__ __launch_bounds__(256) void k_lsm(
    const float* __restrict__ logits, float* __restrict__ out, int N) {
  int wave = (int)((blockIdx.x * (size_t)blockDim.x + threadIdx.x) >> 6);
  int lane = threadIdx.x & 63;
  if (wave >= N) return;
  bool act = lane < NC;
  float v = act ? __builtin_nontemporal_load(logits + (size_t)wave * NC + lane) : -3.0e38f;
  float m = v;
#pragma unroll
  for (int o = 32; o > 0; o >>= 1) m = fmaxf(m, __shfl_xor(m, o, 64));
  float ex = act ? expf(v - m) : 0.f;
  float ssum = ex;
#pragma unroll
  for (int o = 32; o > 0; o >>= 1) ssum += __shfl_xor(ssum, o, 64);
  float lse = m + logf(ssum);
  if (act) __builtin_nontemporal_store(v - lse, out + (size_t)wave * NC + lane);
}

extern "C" void kernel_launch(void* const* d_in, const int* in_sizes, int n_in,
                              void* d_out, int out_size, void* d_ws, size_t ws_size,
                              hipStream_t stream) {
  const float* x = (const float*)d_in[0];
  const int* ei  = (const int*)d_in[1];   // [2][E] flat: rows then cols
  const float* W = (const float*)d_in[2];
  const float* b = (const float*)d_in[3];
  // d_in[4] is K; reference fixes K=2 — hardcoded.
  float* out = (float*)d_out;

  const int N = in_sizes[0] / DF;
  const int E = in_sizes[1] / 2;
  const int NB = (N + RSZ - 1) >> RB;     // 391 buckets for N=100K (<= 512)
  const int* row  = ei;
  const int* colv = ei + E;

  char* basep = (char*)d_ws;
  auto alloc = [&](size_t bytes) {
    char* p = basep;
    basep += (bytes + 511) & ~(size_t)511;
    return p;
  };
  int*   cnt    = (int*)  alloc(((size_t)NB) * 4);
  int*   bbase  = (int*)  alloc(((size_t)NB + 1) * 4);
  unsigned int* slab = (unsigned int*)alloc((size_t)NB * CAP * 4);  // 19.2 MB
  int*   off    = (int*)  alloc(((size_t)N + 1) * 4);
  int*   eidx   = (int*)  alloc((size_t)E * 4);
  float* dinv   = (float*)alloc((size_t)N * 4);
  unsigned short* g0 = (unsigned short*)alloc((size_t)N * NC * 2);  // 8 MB, 2 planes
  unsigned short* g1 = (unsigned short*)alloc((size_t)N * NC * 2);
  // logits [N][NC] f32 aliases the slab: slab is dead after k_binC, and
  // NB*CAP*4 = N*192 B >= N*160 B always. Stream order guarantees safety.
  float* logits = (float*)slab;

  const int gBin = (E + CHUNK - 1) / CHUNK;

  // CSR build: slab binning, then per-bucket finalize
  hipMemsetAsync(cnt, 0, (size_t)NB * 4, stream);
  k_binB<<<gBin, 512, 0, stream>>>(row, colv, cnt, slab, E, NB);
  k_bucket_scan<<<1, 512, 0, stream>>>(cnt, bbase, off, NB, N, E);
  k_binC<<<NB, 512, 0, stream>>>(slab, bbase, off, eidx, dinv, N);

  // project 128 -> 40 first (propagation commutes with the linear layer)
  k_xw_scale<<<(N + 127) / 128, 128, 0, stream>>>(x, W, dinv, g0, N);

  // two hops, each split into two XCD-affine class-plane passes in one grid
  const int NBH = (N + 3) >> 2;         // 4 nodes (waves) per block per plane
  const int NBH4 = (NBH + 3) & ~3;
  const int gHop = 2 * NBH4;            // multiple of 8: clean XCD round-robin
  k_hop<0><<<gHop, 256, 0, stream>>>(off, eidx, dinv, g0, g1, nullptr, nullptr, N, NBH);
  k_hop<1><<<gHop, 256, 0, stream>>>(off, eidx, dinv, g1, nullptr, logits, b, N, NBH);

  // fused bias already applied; log_softmax epilogue
  const int gLsm = (int)(((size_t)N * 64 + 255) / 256);
  k_lsm<<<gLsm, 256, 0, stream>>>(logits, out, N);
}

// Round 3
// 388.366 us; speedup vs baseline: 1.1537x; 1.1537x over previous
//
#include <hip/hip_runtime.h>
#include <hip/hip_bf16.h>
#include <math.h>

#define DF 128
#define NC 40
#define PC 20            // classes per plane (2 planes: 40 B rows -> 4 MB/plane, fits one XCD L2)
#define RB 8             // bucket = node >> 8 (256 nodes/bucket)
#define RSZ 256
#define CHUNK 4096       // edges per binning block
#define CAP 12288        // slab capacity per bucket

typedef float f32x4 __attribute__((ext_vector_type(4)));

__device__ __forceinline__ float bf2f(unsigned short h) {
  unsigned int u = ((unsigned int)h) << 16;
  union { unsigned int u; float f; } c; c.u = u; return c.f;
}
__device__ __forceinline__ unsigned short f2bf(float x) {  // round-to-nearest-even
  union { float f; unsigned int u; } c; c.f = x;
  unsigned int u = c.u;
  return (unsigned short)((u + 0x7fffu + ((u >> 16) & 1u)) >> 16);
}
// unpack a dword holding two packed bf16 (lo = bits 0-15, hi = bits 16-31)
__device__ __forceinline__ float blo(unsigned int u) {
  union { unsigned int u; float f; } c; c.u = u << 16; return c.f;
}
__device__ __forceinline__ float bhi(unsigned int u) {
  union { unsigned int u; float f; } c; c.u = u & 0xffff0000u; return c.f;
}

// ---------- pass B: bin edges into per-bucket slab, count totals ----------
__global__ __launch_bounds__(512) void k_binB(
    const int* __restrict__ row, const int* __restrict__ col,
    int* __restrict__ cnt, unsigned int* __restrict__ slab, int E, int NB) {
  __shared__ int colS[CHUNK];   // 16 KB
  __shared__ int hist[512];
  __shared__ int cursor[512];
  int t = threadIdx.x;
  if (t < NB) hist[t] = 0;
  int s = blockIdx.x * CHUNK, e = min(E, s + CHUNK), n = e - s;
  for (int i = t; i < n; i += 512) colS[i] = col[s + i];
  __syncthreads();
  for (int i = t; i < n; i += 512) atomicAdd(&hist[colS[i] >> RB], 1);
  __syncthreads();
  if (t < NB) cursor[t] = hist[t] ? atomicAdd(&cnt[t], hist[t]) : 0;
  __syncthreads();
  for (int i = t; i < n; i += 512) {
    int c = colS[i];
    int b = c >> RB;
    int p = atomicAdd(&cursor[b], 1);
    slab[(size_t)b * CAP + p] = ((unsigned int)row[s + i] << RB) | (unsigned int)(c & (RSZ - 1));
  }
}

// ---------- bucket base scan (single block; NB <= 512) ----------
__global__ __launch_bounds__(512) void k_bucket_scan(
    const int* __restrict__ cnt, int* __restrict__ base,
    int* __restrict__ off, int NB, int N, int E) {
  __shared__ int s[512];
  int t = threadIdx.x;
  int v = (t < NB) ? cnt[t] : 0;
  s[t] = v;
  __syncthreads();
  for (int o = 1; o < 512; o <<= 1) {
    int u = (t >= o) ? s[t - o] : 0;
    __syncthreads();
    s[t] += u;
    __syncthreads();
  }
  if (t < NB) base[t] = s[t] - v;  // exclusive
  if (t == 0) { base[NB] = E; off[N] = E; }
}

// ---------- pass C: per-bucket CSR finalize + dinv ----------
__global__ __launch_bounds__(512) void k_binC(
    const unsigned int* __restrict__ slab, const int* __restrict__ base,
    int* __restrict__ off, int* __restrict__ eidx, float* __restrict__ dinv, int N) {
  __shared__ int hist[RSZ];
  __shared__ int sc[RSZ];
  __shared__ int cur[RSZ];
  int b = blockIdx.x;
  int t = threadIdx.x;
  if (t < RSZ) hist[t] = 0;
  __syncthreads();
  int cb = base[b], ce = base[b + 1];
  int cnt_b = ce - cb;
  const unsigned int* src = slab + (size_t)b * CAP;
  for (int i = t; i < cnt_b; i += 512) atomicAdd(&hist[src[i] & (RSZ - 1)], 1);
  __syncthreads();
  int v = (t < RSZ) ? hist[t] : 0;
  if (t < RSZ) sc[t] = v;
  __syncthreads();
  for (int o = 1; o < RSZ; o <<= 1) {
    int u = (t < RSZ && t >= o) ? sc[t - o] : 0;
    __syncthreads();
    if (t < RSZ) sc[t] += u;
    __syncthreads();
  }
  if (t < RSZ) {
    int pos = cb + sc[t] - v;
    int node = (b << RB) + t;
    if (node < N) {
      off[node] = pos;
      dinv[node] = rsqrtf((float)v + 2.0f);  // degree + 2 self-loops
    }
    cur[t] = pos;
  }
  __syncthreads();
  for (int i = t; i < cnt_b; i += 512) {
    unsigned int en = src[i];
    int p = atomicAdd(&cur[en & (RSZ - 1)], 1);
    eidx[p] = (int)(en >> RB);
  }
}

// ---------- projection first: g0 planes = bf16( dinv[n] * (x[n] @ W^T) ) ----------
// plane p (p=0,1) holds classes [p*20, p*20+20) as 40 B rows: base = g0 + p*N*PC ushorts
__global__ __launch_bounds__(128) void k_xw_scale(
    const float* __restrict__ x, const float* __restrict__ W,
    const float* __restrict__ dinv, unsigned short* __restrict__ g0, int N) {
  __shared__ float4 Ws[NC * (DF / 4)];  // 20 KB
  for (int i = threadIdx.x; i < NC * (DF / 4); i += blockDim.x)
    Ws[i] = ((const float4*)W)[i];
  __syncthreads();
  int node = blockIdx.x * blockDim.x + threadIdx.x;
  if (node >= N) return;
  float acc[NC];
#pragma unroll
  for (int c = 0; c < NC; ++c) acc[c] = 0.f;
  const float4* xr = (const float4*)(x + (size_t)node * DF);
#pragma unroll 1
  for (int ch = 0; ch < 8; ++ch) {
    float4 v0 = xr[ch * 4 + 0];
    float4 v1 = xr[ch * 4 + 1];
    float4 v2 = xr[ch * 4 + 2];
    float4 v3 = xr[ch * 4 + 3];
#pragma unroll
    for (int c = 0; c < NC; ++c) {
      float4 w0 = Ws[c * (DF / 4) + ch * 4 + 0];
      float4 w1 = Ws[c * (DF / 4) + ch * 4 + 1];
      float4 w2 = Ws[c * (DF / 4) + ch * 4 + 2];
      float4 w3 = Ws[c * (DF / 4) + ch * 4 + 3];
      acc[c] += (v0.x * w0.x + v0.y * w0.y + v0.z * w0.z + v0.w * w0.w) +
                (v1.x * w1.x + v1.y * w1.y + v1.z * w1.z + v1.w * w1.w) +
                (v2.x * w2.x + v2.y * w2.y + v2.z * w2.z + v2.w * w2.w) +
                (v3.x * w3.x + v3.y * w3.y + v3.z * w3.z + v3.w * w3.w);
    }
  }
  float di = dinv[node];
  unsigned int pk[NC / 2];
#pragma unroll
  for (int c2 = 0; c2 < NC / 2; ++c2) {
    unsigned int lo = f2bf(di * acc[c2 * 2 + 0]);
    unsigned int hi = f2bf(di * acc[c2 * 2 + 1]);
    pk[c2] = lo | (hi << 16);
  }
  uint2* p0 = (uint2*)g0 + (size_t)node * 5;
  uint2* p1 = (uint2*)g0 + (size_t)N * 5 + (size_t)node * 5;
#pragma unroll
  for (int q = 0; q < 5; ++q) {
    p0[q] = make_uint2(pk[2 * q], pk[2 * q + 1]);
    p1[q] = make_uint2(pk[10 + 2 * q], pk[10 + 2 * q + 1]);
  }
}

// ---------- hop kernel: one wave = one node x one class-plane (20 classes) ----------
// 12 edge slots x 5 lanes; each lane loads a uint2 (4 classes, 8 B).
// Main loop: 4 independent 12-edge batches (48 edges) per iteration, indices
// clamped to the last valid edge and contributions masked -> straight-line,
// 4 gathers + 4 eidx loads in flight (restores the MLP lost in round 2).
// Block->plane assignment rides blockIdx%8 so XCDs 0-3 only touch plane 0,
// XCDs 4-7 only plane 1 (round-robin dispatch heuristic; correctness-safe).
template<int FINAL>
__global__ __launch_bounds__(256) void k_hop(
    const int* __restrict__ off, const int* __restrict__ eidx,
    const float* __restrict__ dinv, const unsigned short* __restrict__ gin,
    unsigned short* __restrict__ gout, float* __restrict__ logits,
    const float* __restrict__ bias, int N, int NBH) {
  int bid = blockIdx.x;
  int slot8 = bid & 7;
  int half = slot8 >> 2;                       // plane id 0/1
  int nbi = ((bid >> 3) << 2) + (slot8 & 3);   // node-block index within plane
  if (nbi >= NBH) return;
  int lane = threadIdx.x & 63;
  int node = (nbi << 2) + (threadIdx.x >> 6);
  if (node >= N) return;
  int slot = lane / 5;                         // edge slot 0..11 (lanes 60-63 -> 12, masked)
  unsigned j = (unsigned)(lane - slot * 5);    // uint2 index within 40 B row
  const uint2* plane = (const uint2*)gin + (size_t)half * ((size_t)N * 5);
  int s = __builtin_amdgcn_readfirstlane(off[node]);
  int e = __builtin_amdgcn_readfirstlane(off[node + 1]);
  float di = dinv[node];                       // hoisted: overlaps gather latency
  float4 bb;
  if (FINAL) bb = ((const float4*)bias)[half * 5 + (int)j];
  float a00 = 0.f, a01 = 0.f, a02 = 0.f, a03 = 0.f;
  float a10 = 0.f, a11 = 0.f, a12 = 0.f, a13 = 0.f;
  float a20 = 0.f, a21 = 0.f, a22 = 0.f, a23 = 0.f;
  float a30 = 0.f, a31 = 0.f, a32 = 0.f, a33 = 0.f;
  unsigned selfoff = (unsigned)node * 5u + j;
  if (slot == 0) {                             // double self-loop term (independent load)
    uint2 v = plane[selfoff];
    a00 = 2.f * blo(v.x); a01 = 2.f * bhi(v.x);
    a02 = 2.f * blo(v.y); a03 = 2.f * bhi(v.y);
  }
  int last = e - 1;
  bool act = slot < 12;
  for (int i = s; i < e; i += 48) {
    int p0 = i + slot;
    int p1 = p0 + 12, p2 = p0 + 24, p3 = p0 + 36;
    int q0 = min(p0, last), q1 = min(p1, last), q2 = min(p2, last), q3 = min(p3, last);
    int r0 = __builtin_nontemporal_load(eidx + q0);
    int r1 = __builtin_nontemporal_load(eidx + q1);
    int r2 = __builtin_nontemporal_load(eidx + q2);
    int r3 = __builtin_nontemporal_load(eidx + q3);
    uint2 v0 = plane[(unsigned)r0 * 5u + j];
    uint2 v1 = plane[(unsigned)r1 * 5u + j];
    uint2 v2 = plane[(unsigned)r2 * 5u + j];
    uint2 v3 = plane[(unsigned)r3 * 5u + j];
    float m0 = (act && p0 < e) ? 1.f : 0.f;
    float m1 = (act && p1 < e) ? 1.f : 0.f;
    float m2 = (act && p2 < e) ? 1.f : 0.f;
    float m3 = (act && p3 < e) ? 1.f : 0.f;
    a00 += m0 * blo(v0.x); a01 += m0 * bhi(v0.x); a02 += m0 * blo(v0.y); a03 += m0 * bhi(v0.y);
    a10 += m1 * blo(v1.x); a11 += m1 * bhi(v1.x); a12 += m1 * blo(v1.y); a13 += m1 * bhi(v1.y);
    a20 += m2 * blo(v2.x); a21 += m2 * bhi(v2.x); a22 += m2 * blo(v2.y); a23 += m2 * bhi(v2.y);
    a30 += m3 * blo(v3.x); a31 += m3 * bhi(v3.x); a32 += m3 * blo(v3.y); a33 += m3 * bhi(v3.y);
  }
  float a0 = (a00 + a10) + (a20 + a30);
  float a1 = (a01 + a11) + (a21 + a31);
  float a2 = (a02 + a12) + (a22 + a32);
  float a3 = (a03 + a13) + (a23 + a33);
  // reduce the 12 edge slots (lane stride 5) down to lanes 0..4
  int l30 = (lane + 30) & 63, l15 = (lane + 15) & 63;
  a0 += __shfl(a0, l30, 64); a1 += __shfl(a1, l30, 64);
  a2 += __shfl(a2, l30, 64); a3 += __shfl(a3, l30, 64);
  a0 += __shfl(a0, l15, 64); a1 += __shfl(a1, l15, 64);
  a2 += __shfl(a2, l15, 64); a3 += __shfl(a3, l15, 64);
  int l5 = (lane + 5) & 63, l10 = (lane + 10) & 63;
  a0 = a0 + __shfl(a0, l5, 64) + __shfl(a0, l10, 64);
  a1 = a1 + __shfl(a1, l5, 64) + __shfl(a1, l10, 64);
  a2 = a2 + __shfl(a2, l5, 64) + __shfl(a2, l10, 64);
  a3 = a3 + __shfl(a3, l5, 64) + __shfl(a3, l10, 64);
  if (slot == 0) {                             // lanes 0..4 hold classes 4j..4j+3 of this plane
    if (FINAL) {
      f32x4 lg = { di * a0 + bb.x, di * a1 + bb.y,
                   di * a2 + bb.z, di * a3 + bb.w };
      f32x4* dst = (f32x4*)(logits + (size_t)node * NC + half * PC + 4u * j);
      __builtin_nontemporal_store(lg, dst);    // streamed; don't evict the plane
    } else {
      float sc = di * di;
      unsigned lo = (unsigned)f2bf(sc * a0) | ((unsigned)f2bf(sc * a1) << 16);
      unsigned hi = (unsigned)f2bf(sc * a2) | ((unsigned)f2bf(sc * a3) << 16);
      unsigned long long pk = (unsigned long long)lo | ((unsigned long long)hi << 32);
      unsigned long long* dst =
          (unsigned long long*)((uint2*)gout + (size_t)half * ((size_t)N * 5) + selfoff);
      __builtin_nontemporal_store(pk, dst);
    }
  }
}

// ---------- epilogue: log_softmax over f32 logits ----------
__global__ __launch_bounds__(256) void k_lsm(
    const float* __restrict__ logits, float* __restrict__ out, int N) {
  int wave = (int)((blockIdx.x * (size_t)blockDim.x + threadIdx.x) >> 6);
  int lane = threadIdx.x & 63;
  if (wave >= N) return;
  bool act = lane < NC;
  float v = act ? __builtin_nontemporal_load(logits + (size_t)wave * NC + lane) : -3.0e38f;
  float m = v;
#pragma unroll
  for (int o = 32; o > 0; o >>= 1) m = fmaxf(m, __shfl_xor(m, o, 64));
  float ex = act ? expf(v - m) : 0.f;
  float ssum = ex;
#pragma unroll
  for (int o = 32; o > 0; o >>= 1) ssum += __shfl_xor(ssum, o, 64);
  float lse = m + logf(ssum);
  if (act) __builtin_nontemporal_store(v - lse, out + (size_t)wave * NC + lane);
}

extern "C" void kernel_launch(void* const* d_in, const int* in_sizes, int n_in,
                              void* d_out, int out_size, void* d_ws, size_t ws_size,
                              hipStream_t stream) {
  const float* x = (const float*)d_in[0];
  const int* ei  = (const int*)d_in[1];   // [2][E] flat: rows then cols
  const float* W = (const float*)d_in[2];
  const float* b = (const float*)d_in[3];
  // d_in[4] is K; reference fixes K=2 — hardcoded.
  float* out = (float*)d_out;

  const int N = in_sizes[0] / DF;
  const int E = in_sizes[1] / 2;
  const int NB = (N + RSZ - 1) >> RB;     // 391 buckets for N=100K (<= 512)
  const int* row  = ei;
  const int* colv = ei + E;

  char* basep = (char*)d_ws;
  auto alloc = [&](size_t bytes) {
    char* p = basep;
    basep += (bytes + 511) & ~(size_t)511;
    return p;
  };
  int*   cnt    = (int*)  alloc(((size_t)NB) * 4);
  int*   bbase  = (int*)  alloc(((size_t)NB + 1) * 4);
  unsigned int* slab = (unsigned int*)alloc((size_t)NB * CAP * 4);  // 19.2 MB
  int*   off    = (int*)  alloc(((size_t)N + 1) * 4);
  int*   eidx   = (int*)  alloc((size_t)E * 4);
  float* dinv   = (float*)alloc((size_t)N * 4);
  unsigned short* g0 = (unsigned short*)alloc((size_t)N * NC * 2);  // 8 MB, 2 planes
  unsigned short* g1 = (unsigned short*)alloc((size_t)N * NC * 2);
  // logits [N][NC] f32 aliases the slab: slab is dead after k_binC, and
  // NB*CAP*4 = N*192 B >= N*160 B always. Stream order guarantees safety.
  float* logits = (float*)slab;

  const int gBin = (E + CHUNK - 1) / CHUNK;

  // CSR build: slab binning, then per-bucket finalize
  hipMemsetAsync(cnt, 0, (size_t)NB * 4, stream);
  k_binB<<<gBin, 512, 0, stream>>>(row, colv, cnt, slab, E, NB);
  k_bucket_scan<<<1, 512, 0, stream>>>(cnt, bbase, off, NB, N, E);
  k_binC<<<NB, 512, 0, stream>>>(slab, bbase, off, eidx, dinv, N);

  // project 128 -> 40 first (propagation commutes with the linear layer)
  k_xw_scale<<<(N + 127) / 128, 128, 0, stream>>>(x, W, dinv, g0, N);

  // two hops, each split into two XCD-affine class-plane passes in one grid
  const int NBH = (N + 3) >> 2;         // 4 nodes (waves) per block per plane
  const int NBH4 = (NBH + 3) & ~3;
  const int gHop = 2 * NBH4;            // multiple of 8: clean XCD round-robin
  k_hop<0><<<gHop, 256, 0, stream>>>(off, eidx, dinv, g0, g1, nullptr, nullptr, N, NBH);
  k_hop<1><<<gHop, 256, 0, stream>>>(off, eidx, dinv, g1, nullptr, logits, b, N, NBH);

  // fused bias already applied; log_softmax epilogue
  const int gLsm = (int)(((size_t)N * 64 + 255) / 256);
  k_lsm<<<gLsm, 256, 0, stream>>>(logits, out, N);
}

// Round 4
// 370.938 us; speedup vs baseline: 1.2079x; 1.0470x over previous
//
#include <hip/hip_runtime.h>
#include <hip/hip_bf16.h>
#include <math.h>

#define DF 128
#define NC 40
#define PC 20            // classes per plane (2 planes: 40 B rows -> 4 MB/plane, fits one XCD L2)
#define RB 8             // bucket = node >> 8 (256 nodes/bucket)
#define RSZ 256
#define CHUNK 4096       // edges per binning block
#define CAP 12288        // slab capacity per bucket

typedef float f32x4 __attribute__((ext_vector_type(4)));

__device__ __forceinline__ float bf2f(unsigned short h) {
  unsigned int u = ((unsigned int)h) << 16;
  union { unsigned int u; float f; } c; c.u = u; return c.f;
}
__device__ __forceinline__ unsigned short f2bf(float x) {  // round-to-nearest-even
  union { float f; unsigned int u; } c; c.f = x;
  unsigned int u = c.u;
  return (unsigned short)((u + 0x7fffu + ((u >> 16) & 1u)) >> 16);
}
// unpack a dword holding two packed bf16 (lo = bits 0-15, hi = bits 16-31)
__device__ __forceinline__ float blo(unsigned int u) {
  union { unsigned int u; float f; } c; c.u = u << 16; return c.f;
}
__device__ __forceinline__ float bhi(unsigned int u) {
  union { unsigned int u; float f; } c; c.u = u & 0xffff0000u; return c.f;
}

// ---------- pass B: bin edges into per-bucket slab, count totals ----------
__global__ __launch_bounds__(512) void k_binB(
    const int* __restrict__ row, const int* __restrict__ col,
    int* __restrict__ cnt, unsigned int* __restrict__ slab, int E, int NB) {
  __shared__ int colS[CHUNK];   // 16 KB
  __shared__ int hist[512];
  __shared__ int cursor[512];
  int t = threadIdx.x;
  if (t < NB) hist[t] = 0;
  int s = blockIdx.x * CHUNK, e = min(E, s + CHUNK), n = e - s;
  for (int i = t; i < n; i += 512) colS[i] = col[s + i];
  __syncthreads();
  for (int i = t; i < n; i += 512) atomicAdd(&hist[colS[i] >> RB], 1);
  __syncthreads();
  if (t < NB) cursor[t] = hist[t] ? atomicAdd(&cnt[t], hist[t]) : 0;
  __syncthreads();
  for (int i = t; i < n; i += 512) {
    int c = colS[i];
    int b = c >> RB;
    int p = atomicAdd(&cursor[b], 1);
    slab[(size_t)b * CAP + p] = ((unsigned int)row[s + i] << RB) | (unsigned int)(c & (RSZ - 1));
  }
}

// ---------- bucket base scan (single block; NB <= 512) ----------
__global__ __launch_bounds__(512) void k_bucket_scan(
    const int* __restrict__ cnt, int* __restrict__ base,
    int* __restrict__ off, int NB, int N, int E) {
  __shared__ int s[512];
  int t = threadIdx.x;
  int v = (t < NB) ? cnt[t] : 0;
  s[t] = v;
  __syncthreads();
  for (int o = 1; o < 512; o <<= 1) {
    int u = (t >= o) ? s[t - o] : 0;
    __syncthreads();
    s[t] += u;
    __syncthreads();
  }
  if (t < NB) base[t] = s[t] - v;  // exclusive
  if (t == 0) { base[NB] = E; off[N] = E; }
}

// ---------- pass C: per-bucket CSR finalize + dinv ----------
__global__ __launch_bounds__(512) void k_binC(
    const unsigned int* __restrict__ slab, const int* __restrict__ base,
    int* __restrict__ off, int* __restrict__ eidx, float* __restrict__ dinv, int N) {
  __shared__ int hist[RSZ];
  __shared__ int sc[RSZ];
  __shared__ int cur[RSZ];
  int b = blockIdx.x;
  int t = threadIdx.x;
  if (t < RSZ) hist[t] = 0;
  __syncthreads();
  int cb = base[b], ce = base[b + 1];
  int cnt_b = ce - cb;
  const unsigned int* src = slab + (size_t)b * CAP;
  for (int i = t; i < cnt_b; i += 512) atomicAdd(&hist[src[i] & (RSZ - 1)], 1);
  __syncthreads();
  int v = (t < RSZ) ? hist[t] : 0;
  if (t < RSZ) sc[t] = v;
  __syncthreads();
  for (int o = 1; o < RSZ; o <<= 1) {
    int u = (t < RSZ && t >= o) ? sc[t - o] : 0;
    __syncthreads();
    if (t < RSZ) sc[t] += u;
    __syncthreads();
  }
  if (t < RSZ) {
    int pos = cb + sc[t] - v;
    int node = (b << RB) + t;
    if (node < N) {
      off[node] = pos;
      dinv[node] = rsqrtf((float)v + 2.0f);  // degree + 2 self-loops
    }
    cur[t] = pos;
  }
  __syncthreads();
  for (int i = t; i < cnt_b; i += 512) {
    unsigned int en = src[i];
    int p = atomicAdd(&cur[en & (RSZ - 1)], 1);
    eidx[p] = (int)(en >> RB);
  }
}

// ---------- projection first: g0 planes = bf16( dinv[n] * (x[n] @ W^T) ) ----------
// plane p (p=0,1) holds classes [p*20, p*20+20) as 40 B rows: base = g0 + p*N*PC ushorts
__global__ __launch_bounds__(128) void k_xw_scale(
    const float* __restrict__ x, const float* __restrict__ W,
    const float* __restrict__ dinv, unsigned short* __restrict__ g0, int N) {
  __shared__ float4 Ws[NC * (DF / 4)];  // 20 KB
  for (int i = threadIdx.x; i < NC * (DF / 4); i += blockDim.x)
    Ws[i] = ((const float4*)W)[i];
  __syncthreads();
  int node = blockIdx.x * blockDim.x + threadIdx.x;
  if (node >= N) return;
  float acc[NC];
#pragma unroll
  for (int c = 0; c < NC; ++c) acc[c] = 0.f;
  const float4* xr = (const float4*)(x + (size_t)node * DF);
#pragma unroll 1
  for (int ch = 0; ch < 8; ++ch) {
    float4 v0 = xr[ch * 4 + 0];
    float4 v1 = xr[ch * 4 + 1];
    float4 v2 = xr[ch * 4 + 2];
    float4 v3 = xr[ch * 4 + 3];
#pragma unroll
    for (int c = 0; c < NC; ++c) {
      float4 w0 = Ws[c * (DF / 4) + ch * 4 + 0];
      float4 w1 = Ws[c * (DF / 4) + ch * 4 + 1];
      float4 w2 = Ws[c * (DF / 4) + ch * 4 + 2];
      float4 w3 = Ws[c * (DF / 4) + ch * 4 + 3];
      acc[c] += (v0.x * w0.x + v0.y * w0.y + v0.z * w0.z + v0.w * w0.w) +
                (v1.x * w1.x + v1.y * w1.y + v1.z * w1.z + v1.w * w1.w) +
                (v2.x * w2.x + v2.y * w2.y + v2.z * w2.z + v2.w * w2.w) +
                (v3.x * w3.x + v3.y * w3.y + v3.z * w3.z + v3.w * w3.w);
    }
  }
  float di = dinv[node];
  unsigned int pk[NC / 2];
#pragma unroll
  for (int c2 = 0; c2 < NC / 2; ++c2) {
    unsigned int lo = f2bf(di * acc[c2 * 2 + 0]);
    unsigned int hi = f2bf(di * acc[c2 * 2 + 1]);
    pk[c2] = lo | (hi << 16);
  }
  uint2* p0 = (uint2*)g0 + (size_t)node * 5;
  uint2* p1 = (uint2*)g0 + (size_t)N * 5 + (size_t)node * 5;
#pragma unroll
  for (int q = 0; q < 5; ++q) {
    p0[q] = make_uint2(pk[2 * q], pk[2 * q + 1]);
    p1[q] = make_uint2(pk[10 + 2 * q], pk[10 + 2 * q + 1]);
  }
}

// ---------- hop kernel: one wave = TWO consecutive nodes x one class-plane ----------
// 12 edge slots x 5 lanes; each lane loads a uint2 (4 classes, 8 B).
// Per node: one 48-edge masked shot (4 batches, accumulator sets P/Q); both
// nodes' 8 eidx loads + 8 gathers issue back-to-back (2x MLP vs round 3);
// CSR adjacency gives off[nB] == off[nA+1] -> 3 descriptor loads for 2 nodes;
// the two shuffle-reduce chains are independent and interleave.
// Block->plane assignment rides blockIdx%8 so XCDs 0-3 only touch plane 0,
// XCDs 4-7 only plane 1 (round-robin dispatch heuristic; correctness-safe).
template<int FINAL>
__global__ __launch_bounds__(256) void k_hop(
    const int* __restrict__ off, const int* __restrict__ eidx,
    const float* __restrict__ dinv, const unsigned short* __restrict__ gin,
    unsigned short* __restrict__ gout, float* __restrict__ logits,
    const float* __restrict__ bias, int N, int NBH) {
  int bid = blockIdx.x;
  int slot8 = bid & 7;
  int half = slot8 >> 2;                       // plane id 0/1
  int nbi = ((bid >> 3) << 2) + (slot8 & 3);   // node-block index within plane
  if (nbi >= NBH) return;
  int lane = threadIdx.x & 63;
  int nA = (nbi << 3) + ((threadIdx.x >> 6) << 1);  // 8 nodes/block, 2 per wave
  if (nA >= N) return;
  bool hasB = (nA + 1) < N;
  int nBs = hasB ? nA + 1 : nA;
  int slot = lane / 5;                         // edge slot 0..11 (lanes 60-63 -> 12, masked)
  unsigned j = (unsigned)(lane - slot * 5);    // uint2 index within 40 B row
  bool act = slot < 12;
  const uint2* plane = (const uint2*)gin + (size_t)half * ((size_t)N * 5);
  int sA = __builtin_amdgcn_readfirstlane(off[nA]);
  int eA = __builtin_amdgcn_readfirstlane(off[nA + 1]);
  int sB = eA;                                  // CSR: off[nB] == off[nA+1]
  int eB = eA;
  if (hasB) eB = __builtin_amdgcn_readfirstlane(off[nA + 2]);
  float diA = dinv[nA];
  float diB = dinv[nBs];
  float4 bb;
  if (FINAL) bb = ((const float4*)bias)[half * 5 + (int)j];
  // per node: accumulator sets P (batches 0,1 + self) and Q (batches 2,3)
  float A0 = 0.f, A1 = 0.f, A2 = 0.f, A3 = 0.f, A4 = 0.f, A5 = 0.f, A6 = 0.f, A7 = 0.f;
  float B0 = 0.f, B1 = 0.f, B2 = 0.f, B3 = 0.f, B4 = 0.f, B5 = 0.f, B6 = 0.f, B7 = 0.f;
  unsigned selfA = (unsigned)nA * 5u + j;
  unsigned selfB = (unsigned)nBs * 5u + j;
  if (slot == 0) {                             // double self-loop terms
    uint2 vA = plane[selfA];
    uint2 vB = plane[selfB];
    A0 = 2.f * blo(vA.x); A1 = 2.f * bhi(vA.x); A2 = 2.f * blo(vA.y); A3 = 2.f * bhi(vA.y);
    B0 = 2.f * blo(vB.x); B1 = 2.f * bhi(vB.x); B2 = 2.f * blo(vB.y); B3 = 2.f * bhi(vB.y);
  }
  int lastA = (eA > sA) ? eA - 1 : 0;
  int lastB = (eB > sB) ? eB - 1 : 0;
  {  // combined 48-edge shot for BOTH nodes: 8 eidx loads + 8 gathers in flight
    int pa0 = sA + slot, pa1 = pa0 + 12, pa2 = pa0 + 24, pa3 = pa0 + 36;
    int pb0 = sB + slot, pb1 = pb0 + 12, pb2 = pb0 + 24, pb3 = pb0 + 36;
    int ra0 = __builtin_nontemporal_load(eidx + min(pa0, lastA));
    int ra1 = __builtin_nontemporal_load(eidx + min(pa1, lastA));
    int ra2 = __builtin_nontemporal_load(eidx + min(pa2, lastA));
    int ra3 = __builtin_nontemporal_load(eidx + min(pa3, lastA));
    int rb0 = __builtin_nontemporal_load(eidx + min(pb0, lastB));
    int rb1 = __builtin_nontemporal_load(eidx + min(pb1, lastB));
    int rb2 = __builtin_nontemporal_load(eidx + min(pb2, lastB));
    int rb3 = __builtin_nontemporal_load(eidx + min(pb3, lastB));
    uint2 va0 = plane[(unsigned)ra0 * 5u + j];
    uint2 va1 = plane[(unsigned)ra1 * 5u + j];
    uint2 va2 = plane[(unsigned)ra2 * 5u + j];
    uint2 va3 = plane[(unsigned)ra3 * 5u + j];
    uint2 vb0 = plane[(unsigned)rb0 * 5u + j];
    uint2 vb1 = plane[(unsigned)rb1 * 5u + j];
    uint2 vb2 = plane[(unsigned)rb2 * 5u + j];
    uint2 vb3 = plane[(unsigned)rb3 * 5u + j];
    float ma0 = (act && pa0 < eA) ? 1.f : 0.f;
    float ma1 = (act && pa1 < eA) ? 1.f : 0.f;
    float ma2 = (act && pa2 < eA) ? 1.f : 0.f;
    float ma3 = (act && pa3 < eA) ? 1.f : 0.f;
    float mb0 = (act && pb0 < eB) ? 1.f : 0.f;
    float mb1 = (act && pb1 < eB) ? 1.f : 0.f;
    float mb2 = (act && pb2 < eB) ? 1.f : 0.f;
    float mb3 = (act && pb3 < eB) ? 1.f : 0.f;
    A0 += ma0 * blo(va0.x); A1 += ma0 * bhi(va0.x); A2 += ma0 * blo(va0.y); A3 += ma0 * bhi(va0.y);
    A0 += ma1 * blo(va1.x); A1 += ma1 * bhi(va1.x); A2 += ma1 * blo(va1.y); A3 += ma1 * bhi(va1.y);
    A4 += ma2 * blo(va2.x); A5 += ma2 * bhi(va2.x); A6 += ma2 * blo(va2.y); A7 += ma2 * bhi(va2.y);
    A4 += ma3 * blo(va3.x); A5 += ma3 * bhi(va3.x); A6 += ma3 * blo(va3.y); A7 += ma3 * bhi(va3.y);
    B0 += mb0 * blo(vb0.x); B1 += mb0 * bhi(vb0.x); B2 += mb0 * blo(vb0.y); B3 += mb0 * bhi(vb0.y);
    B0 += mb1 * blo(vb1.x); B1 += mb1 * bhi(vb1.x); B2 += mb1 * blo(vb1.y); B3 += mb1 * bhi(vb1.y);
    B4 += mb2 * blo(vb2.x); B5 += mb2 * bhi(vb2.x); B6 += mb2 * blo(vb2.y); B7 += mb2 * bhi(vb2.y);
    B4 += mb3 * blo(vb3.x); B5 += mb3 * bhi(vb3.x); B6 += mb3 * blo(vb3.y); B7 += mb3 * bhi(vb3.y);
  }
  // rare cleanup (deg > 48, ~0.3% of nodes): rolled 12-edge masked batches
  for (int i = sA + 48; i < eA; i += 12) {
    int p = i + slot;
    int r = __builtin_nontemporal_load(eidx + min(p, lastA));
    uint2 v = plane[(unsigned)r * 5u + j];
    float m = (act && p < eA) ? 1.f : 0.f;
    A0 += m * blo(v.x); A1 += m * bhi(v.x); A2 += m * blo(v.y); A3 += m * bhi(v.y);
  }
  for (int i = sB + 48; i < eB; i += 12) {
    int p = i + slot;
    int r = __builtin_nontemporal_load(eidx + min(p, lastB));
    uint2 v = plane[(unsigned)r * 5u + j];
    float m = (act && p < eB) ? 1.f : 0.f;
    B0 += m * blo(v.x); B1 += m * bhi(v.x); B2 += m * blo(v.y); B3 += m * bhi(v.y);
  }
  float a0 = A0 + A4, a1 = A1 + A5, a2 = A2 + A6, a3 = A3 + A7;
  float b0 = B0 + B4, b1 = B1 + B5, b2 = B2 + B6, b3 = B3 + B7;
  // reduce the 12 edge slots (lane stride 5) down to lanes 0..4; A and B chains
  // are independent -> interleaved issue hides bpermute latency
  int l30 = (lane + 30) & 63, l15 = (lane + 15) & 63;
  a0 += __shfl(a0, l30, 64); b0 += __shfl(b0, l30, 64);
  a1 += __shfl(a1, l30, 64); b1 += __shfl(b1, l30, 64);
  a2 += __shfl(a2, l30, 64); b2 += __shfl(b2, l30, 64);
  a3 += __shfl(a3, l30, 64); b3 += __shfl(b3, l30, 64);
  a0 += __shfl(a0, l15, 64); b0 += __shfl(b0, l15, 64);
  a1 += __shfl(a1, l15, 64); b1 += __shfl(b1, l15, 64);
  a2 += __shfl(a2, l15, 64); b2 += __shfl(b2, l15, 64);
  a3 += __shfl(a3, l15, 64); b3 += __shfl(b3, l15, 64);
  int l5 = (lane + 5) & 63, l10 = (lane + 10) & 63;
  a0 = a0 + __shfl(a0, l5, 64) + __shfl(a0, l10, 64);
  b0 = b0 + __shfl(b0, l5, 64) + __shfl(b0, l10, 64);
  a1 = a1 + __shfl(a1, l5, 64) + __shfl(a1, l10, 64);
  b1 = b1 + __shfl(b1, l5, 64) + __shfl(b1, l10, 64);
  a2 = a2 + __shfl(a2, l5, 64) + __shfl(a2, l10, 64);
  b2 = b2 + __shfl(b2, l5, 64) + __shfl(b2, l10, 64);
  a3 = a3 + __shfl(a3, l5, 64) + __shfl(a3, l10, 64);
  b3 = b3 + __shfl(b3, l5, 64) + __shfl(b3, l10, 64);
  if (slot == 0) {                             // lanes 0..4 hold classes 4j..4j+3
    if (FINAL) {
      f32x4 lgA = { diA * a0 + bb.x, diA * a1 + bb.y, diA * a2 + bb.z, diA * a3 + bb.w };
      f32x4* dA = (f32x4*)(logits + (size_t)nA * NC + half * PC + 4u * j);
      __builtin_nontemporal_store(lgA, dA);
      if (hasB) {
        f32x4 lgB = { diB * b0 + bb.x, diB * b1 + bb.y, diB * b2 + bb.z, diB * b3 + bb.w };
        f32x4* dB = (f32x4*)(logits + (size_t)nBs * NC + half * PC + 4u * j);
        __builtin_nontemporal_store(lgB, dB);
      }
    } else {
      float scA = diA * diA;
      unsigned loA = (unsigned)f2bf(scA * a0) | ((unsigned)f2bf(scA * a1) << 16);
      unsigned hiA = (unsigned)f2bf(scA * a2) | ((unsigned)f2bf(scA * a3) << 16);
      unsigned long long pkA = (unsigned long long)loA | ((unsigned long long)hiA << 32);
      unsigned long long* dA =
          (unsigned long long*)((uint2*)gout + (size_t)half * ((size_t)N * 5) + selfA);
      __builtin_nontemporal_store(pkA, dA);
      if (hasB) {
        float scB = diB * diB;
        unsigned loB = (unsigned)f2bf(scB * b0) | ((unsigned)f2bf(scB * b1) << 16);
        unsigned hiB = (unsigned)f2bf(scB * b2) | ((unsigned)f2bf(scB * b3) << 16);
        unsigned long long pkB = (unsigned long long)loB | ((unsigned long long)hiB << 32);
        unsigned long long* dB =
            (unsigned long long*)((uint2*)gout + (size_t)half * ((size_t)N * 5) + selfB);
        __builtin_nontemporal_store(pkB, dB);
      }
    }
  }
}

// ---------- epilogue: log_softmax over f32 logits ----------
__global__ __launch_bounds__(256) void k_lsm(
    const float* __restrict__ logits, float* __restrict__ out, int N) {
  int wave = (int)((blockIdx.x * (size_t)blockDim.x + threadIdx.x) >> 6);
  int lane = threadIdx.x & 63;
  if (wave >= N) return;
  bool act = lane < NC;
  float v = act ? __builtin_nontemporal_load(logits + (size_t)wave * NC + lane) : -3.0e38f;
  float m = v;
#pragma unroll
  for (int o = 32; o > 0; o >>= 1) m = fmaxf(m, __shfl_xor(m, o, 64));
  float ex = act ? expf(v - m) : 0.f;
  float ssum = ex;
#pragma unroll
  for (int o = 32; o > 0; o >>= 1) ssum += __shfl_xor(ssum, o, 64);
  float lse = m + logf(ssum);
  if (act) __builtin_nontemporal_store(v - lse, out + (size_t)wave * NC + lane);
}

extern "C" void kernel_launch(void* const* d_in, const int* in_sizes, int n_in,
                              void* d_out, int out_size, void* d_ws, size_t ws_size,
                              hipStream_t stream) {
  const float* x = (const float*)d_in[0];
  const int* ei  = (const int*)d_in[1];   // [2][E] flat: rows then cols
  const float* W = (const float*)d_in[2];
  const float* b = (const float*)d_in[3];
  // d_in[4] is K; reference fixes K=2 — hardcoded.
  float* out = (float*)d_out;

  const int N = in_sizes[0] / DF;
  const int E = in_sizes[1] / 2;
  const int NB = (N + RSZ - 1) >> RB;     // 391 buckets for N=100K (<= 512)
  const int* row  = ei;
  const int* colv = ei + E;

  char* basep = (char*)d_ws;
  auto alloc = [&](size_t bytes) {
    char* p = basep;
    basep += (bytes + 511) & ~(size_t)511;
    return p;
  };
  int*   cnt    = (int*)  alloc(((size_t)NB) * 4);
  int*   bbase  = (int*)  alloc(((size_t)NB + 1) * 4);
  unsigned int* slab = (unsigned int*)alloc((size_t)NB * CAP * 4);  // 19.2 MB
  int*   off    = (int*)  alloc(((size_t)N + 1) * 4);
  int*   eidx   = (int*)  alloc((size_t)E * 4);
  float* dinv   = (float*)alloc((size_t)N * 4);
  unsigned short* g0 = (unsigned short*)alloc((size_t)N * NC * 2);  // 8 MB, 2 planes
  unsigned short* g1 = (unsigned short*)alloc((size_t)N * NC * 2);
  // logits [N][NC] f32 aliases the slab: slab is dead after k_binC, and
  // NB*CAP*4 = N*192 B >= N*160 B always. Stream order guarantees safety.
  float* logits = (float*)slab;

  const int gBin = (E + CHUNK - 1) / CHUNK;

  // CSR build: slab binning, then per-bucket finalize
  hipMemsetAsync(cnt, 0, (size_t)NB * 4, stream);
  k_binB<<<gBin, 512, 0, stream>>>(row, colv, cnt, slab, E, NB);
  k_bucket_scan<<<1, 512, 0, stream>>>(cnt, bbase, off, NB, N, E);
  k_binC<<<NB, 512, 0, stream>>>(slab, bbase, off, eidx, dinv, N);

  // project 128 -> 40 first (propagation commutes with the linear layer)
  k_xw_scale<<<(N + 127) / 128, 128, 0, stream>>>(x, W, dinv, g0, N);

  // two hops, each split into two XCD-affine class-plane passes in one grid
  const int NBH = (N + 7) >> 3;         // 8 nodes per block (4 waves x 2 nodes)
  const int NBH4 = (NBH + 3) & ~3;
  const int gHop = 2 * NBH4;            // multiple of 8: clean XCD round-robin
  k_hop<0><<<gHop, 256, 0, stream>>>(off, eidx, dinv, g0, g1, nullptr, nullptr, N, NBH);
  k_hop<1><<<gHop, 256, 0, stream>>>(off, eidx, dinv, g1, nullptr, logits, b, N, NBH);

  // fused bias already applied; log_softmax epilogue
  const int gLsm = (int)(((size_t)N * 64 + 255) / 256);
  k_lsm<<<gLsm, 256, 0, stream>>>(logits, out, N);
}